// Round 6
// baseline (227.149 us; speedup 1.0000x reference)
//
#include <hip/hip_runtime.h>
#include <math.h>

#define Bn 64
#define Tn 2048
#define NCLS 20
#define Dn 2048
#define LCSL 64
#define FSDL 32

typedef __bf16 bf16x4 __attribute__((ext_vector_type(4)));
typedef __bf16 bf16x8 __attribute__((ext_vector_type(8)));
typedef float f32x4 __attribute__((ext_vector_type(4)));

// ws float offsets (every consumed slot written each call; no atomics, no counters)
#define WS_LCS 0         // 64   lcs dp results
#define WS_FSD 64        // 64   fsd dp results
#define WS_NORM 128      // 384  feat norms
#define WS_GS 512        // 512  guide/sparse partials [128 blocks][4]
// END = 1024 floats

// block roles (single mega launch, 512 threads/block):
//   [0,128)    guide+sparse partial reductions
//   [128,176)  feature norms (384 rows, wave per row)
//   [176,240)  LCS fused GEMM(64x64,K=2048) + normalize + DP   (1 block per b)
//   [240,304)  FSD fused GEMM(32x32,K=2x1024) + normalize + DP (1 block per b)
#define AUXB 176
#define NBLK 304

__global__ __launch_bounds__(512) void mega_kernel(
    const float* __restrict__ lcs0, const float* __restrict__ lcs1,
    const float* __restrict__ fA0, const float* __restrict__ fA1,
    const float* __restrict__ fB1,
    const float* __restrict__ vid0, const float* __restrict__ vid1,
    const float* __restrict__ cas0, const float* __restrict__ att0,
    const float* __restrict__ cas1, const float* __restrict__ att1,
    const float* __restrict__ f0, const float* __restrict__ f1,
    const float* __restrict__ f2, const float* __restrict__ f3,
    const float* __restrict__ f4, const float* __restrict__ f5,
    float* __restrict__ ws) {
    __shared__ __align__(16) __bf16 tA[2][4096];   // 16 KB
    __shared__ __align__(16) __bf16 tB[2][4096];   // 16 KB
    __shared__ __align__(16) float S[64 * 68];     // 17.4 KB (LCS S | FSD M+G | guide red)
    __shared__ float inv[128];
    const int t = threadIdx.x;
    const int bid = blockIdx.x;
    const int w = t >> 6, lane = t & 63;
    const int quad = lane >> 4, l16 = lane & 15;

    if (bid < 128) {
        // -------- guide + sparse partials --------
        const int gb = bid;
        const int N = Bn * Tn;
        float g0 = 0.f, s0 = 0.f, g1 = 0.f, s1 = 0.f;
        for (int n = gb * 512 + t; n < 2 * N; n += 128 * 512) {
            int sfx = (n >= N);
            int m = sfx ? (n - N) : n;
            const float* cas = sfx ? cas1 : cas0;
            const float* att = sfx ? att1 : att0;
            float a0 = att[m * 3 + 0];
            float a1 = att[m * 3 + 1];
            float g = fabsf(1.0f - cas[m * (NCLS + 1) + NCLS] - a0);
            float s = a0 + a1;
            if (sfx) { g1 += g; s1 += s; } else { g0 += g; s0 += s; }
        }
        float* red = S;   // 4*512 = 2048 floats
        float vals[4] = {g0, s0, g1, s1};
        #pragma unroll
        for (int v = 0; v < 4; ++v) red[v * 512 + t] = vals[v];
        __syncthreads();
        for (int o = 256; o; o >>= 1) {
            if (t < o) {
                #pragma unroll
                for (int v = 0; v < 4; ++v) red[v * 512 + t] += red[v * 512 + t + o];
            }
            __syncthreads();
        }
        if (t < 4) ws[WS_GS + gb * 4 + t] = red[t * 512];
    } else if (bid < AUXB) {
        // -------- feature norms: 384 rows, wave per row (48 blocks x 8 waves) --------
        int R = (bid - 128) * 8 + w;
        const float* arr[6] = {f0, f1, f2, f3, f4, f5};
        const float* p = arr[R >> 6] + (size_t)(R & 63) * Dn;
        float s = 0.f;
        #pragma unroll
        for (int qd = 0; qd < 8; ++qd) {
            float4 v = *(const float4*)(p + qd * 256 + lane * 4);
            s += v.x * v.x + v.y * v.y + v.z * v.z + v.w * v.w;
        }
        for (int off = 32; off; off >>= 1) s += __shfl_down(s, off);
        if (lane == 0) ws[WS_NORM + R] = sqrtf(s);
    } else if (bid < 240) {
        // ======== LCS fused: GEMM 64x64 K=2048 + normalize + DP ========
        const int b = bid - AUXB;
        const float* c0 = lcs0 + (size_t)b * LCSL * Dn;
        const float* c1 = lcs1 + (size_t)b * LCSL * Dn;
        constexpr int KC = 32;   // 32 stages of 64 cols

        f32x4 acc[2] = {};
        float sqa[2] = {0.f, 0.f}, sqb[2] = {0.f, 0.f};
        float4 pA[2], pB[2];

        auto LOADL = [&](int st) {
            #pragma unroll
            for (int l = 0; l < 2; ++l) {
                int idx4 = l * 512 + t;            // 1024 slots = 64 rows x 16 float4
                int row = idx4 >> 4, kq4 = idx4 & 15;
                pA[l] = *(const float4*)(c0 + (size_t)row * Dn + st * 64 + kq4 * 4);
                pB[l] = *(const float4*)(c1 + (size_t)row * Dn + st * 64 + kq4 * 4);
            }
        };
        auto WRITEL = [&](int buf) {
            #pragma unroll
            for (int l = 0; l < 2; ++l) {
                int idx4 = l * 512 + t;
                int row = idx4 >> 4, kq4 = idx4 & 15;
                int c = kq4 >> 1, h = kq4 & 1;
                int pos = row * 64 + ((c ^ (row & 7)) << 3) + h * 4;
                float4 av = pA[l], bv = pB[l];
                bf16x4 a4 = {(__bf16)av.x, (__bf16)av.y, (__bf16)av.z, (__bf16)av.w};
                bf16x4 b4 = {(__bf16)bv.x, (__bf16)bv.y, (__bf16)bv.z, (__bf16)bv.w};
                *(bf16x4*)&tA[buf][pos] = a4;
                *(bf16x4*)&tB[buf][pos] = b4;
                sqa[l] += av.x * av.x + av.y * av.y + av.z * av.z + av.w * av.w;
                sqb[l] += bv.x * bv.x + bv.y * bv.y + bv.z * bv.z + bv.w * bv.w;
            }
        };

        LOADL(0);
        WRITEL(0);
        LOADL(1);
        __syncthreads();
        for (int kc = 0; kc < KC; ++kc) {
            const int cur = kc & 1;
            #pragma unroll
            for (int s = 0; s < 2; ++s) {
                int ar = (w >> 1) * 16 + l16;
                int ac_ = (s * 4 + quad) ^ (ar & 7);
                bf16x8 af = *(const bf16x8*)&tA[cur][ar * 64 + (ac_ << 3)];
                #pragma unroll
                for (int tj = 0; tj < 2; ++tj) {
                    int br = (w & 1) * 32 + tj * 16 + l16;
                    int bc = (s * 4 + quad) ^ (br & 7);
                    bf16x8 bf = *(const bf16x8*)&tB[cur][br * 64 + (bc << 3)];
                    acc[tj] = __builtin_amdgcn_mfma_f32_16x16x32_bf16(af, bf, acc[tj], 0, 0, 0);
                }
            }
            if (kc + 1 < KC) {
                WRITEL(cur ^ 1);
                if (kc + 2 < KC) LOADL(kc + 2);
                __syncthreads();
            }
        }
        // row norms: 16 lanes per row slice
        #pragma unroll
        for (int l = 0; l < 2; ++l) {
            float sa = sqa[l], sb = sqb[l];
            #pragma unroll
            for (int m = 1; m < 16; m <<= 1) {
                sa += __shfl_xor(sa, m);
                sb += __shfl_xor(sb, m);
            }
            if ((t & 15) == 0) {
                int r = l * 32 + (t >> 4);
                inv[r] = sa;
                inv[64 + r] = sb;
            }
        }
        __syncthreads();
        if (t < 128) inv[t] = 1.0f / sqrtf(inv[t]);
        __syncthreads();
        // normalized S into LDS
        #pragma unroll
        for (int tj = 0; tj < 2; ++tj)
            #pragma unroll
            for (int rg = 0; rg < 4; ++rg) {
                int row = (w >> 1) * 16 + quad * 4 + rg;
                int col = (w & 1) * 32 + tj * 16 + l16;
                S[row * 68 + col] = acc[tj][rg] * inv[row] * inv[64 + col];
            }
        __syncthreads();
        // DP (anti-diagonal wavefront, wave 0)
        if (t < 64) {
            float prev = 0.f, prevprev = 0.f;
            float sval_next = S[t * 68 + 0];
            for (int d = 2; d <= 128; ++d) {
                float s = sval_next;
                int jn = d - t - 1;
                if (jn >= 0 && jn < 64) sval_next = S[t * 68 + jn];
                float up = __shfl_up(prev, 1);
                float dg = __shfl_up(prevprev, 1);
                if (t == 0) { up = 0.f; dg = 0.f; }
                int j = d - t - 1;
                float left = prev;
                float val = (s > 0.5f) ? (dg + s) : fmaxf(up, left);
                float cur = (j >= 1 && j <= 64) ? val : 0.f;
                prevprev = prev;
                prev = cur;
            }
            if (t == 63) ws[WS_LCS + b] = prev;
        }
    } else {
        // ======== FSD fused: M then G (32x32, K=1024 each) + DP ========
        const int b = bid - 240;
        float ps = 0.f;
        for (int c = 0; c < NCLS; ++c) ps += vid0[b * NCLS + c] * vid1[b * NCLS + c];
        const float* base1 = (ps > 0.f) ? fA1 : fB1;
        const float* c0 = fA0 + (size_t)b * FSDL * Dn;
        const float* c1 = base1 + (size_t)b * FSDL * Dn;
        const int wi = w >> 1, wj = w & 1;   // waves 0..3 compute MFMA
        float* Ml = S;            // 32*36 = 1152
        float* Gl = S + 1152;     // 1152
        constexpr int KC = 16;    // 16 stages of 64 cols per half

        for (int ph = 0; ph < 2; ++ph) {
            const int off = ph * 1024;
            f32x4 acc = {};
            float sqa = 0.f, sqb = 0.f;
            float4 pA, pB;
            auto LOADF = [&](int st) {
                int row = t >> 4, kq4 = t & 15;     // 512 slots = 32 rows x 16 float4
                pA = *(const float4*)(c0 + (size_t)row * Dn + off + st * 64 + kq4 * 4);
                pB = *(const float4*)(c1 + (size_t)row * Dn + off + st * 64 + kq4 * 4);
            };
            auto WRITEF = [&](int buf) {
                int row = t >> 4, kq4 = t & 15;
                int c = kq4 >> 1, h = kq4 & 1;
                int pos = row * 64 + ((c ^ (row & 7)) << 3) + h * 4;
                float4 av = pA, bv = pB;
                bf16x4 a4 = {(__bf16)av.x, (__bf16)av.y, (__bf16)av.z, (__bf16)av.w};
                bf16x4 b4 = {(__bf16)bv.x, (__bf16)bv.y, (__bf16)bv.z, (__bf16)bv.w};
                *(bf16x4*)&tA[buf][pos] = a4;
                *(bf16x4*)&tB[buf][pos] = b4;
                sqa += av.x * av.x + av.y * av.y + av.z * av.z + av.w * av.w;
                sqb += bv.x * bv.x + bv.y * bv.y + bv.z * bv.z + bv.w * bv.w;
            };

            LOADF(0);
            WRITEF(0);
            LOADF(1);
            __syncthreads();
            for (int kc = 0; kc < KC; ++kc) {
                const int cur = kc & 1;
                if (w < 4) {
                    #pragma unroll
                    for (int s = 0; s < 2; ++s) {
                        int ar = wi * 16 + l16;
                        int ac_ = (s * 4 + quad) ^ (ar & 7);
                        bf16x8 af = *(const bf16x8*)&tA[cur][ar * 64 + (ac_ << 3)];
                        int br = wj * 16 + l16;
                        int bc = (s * 4 + quad) ^ (br & 7);
                        bf16x8 bf = *(const bf16x8*)&tB[cur][br * 64 + (bc << 3)];
                        acc = __builtin_amdgcn_mfma_f32_16x16x32_bf16(af, bf, acc, 0, 0, 0);
                    }
                }
                if (kc + 1 < KC) {
                    WRITEF(cur ^ 1);
                    if (kc + 2 < KC) LOADF(kc + 2);
                    __syncthreads();
                }
            }
            // norms for this half
            {
                float sa = sqa, sb = sqb;
                #pragma unroll
                for (int m = 1; m < 16; m <<= 1) {
                    sa += __shfl_xor(sa, m);
                    sb += __shfl_xor(sb, m);
                }
                if ((t & 15) == 0) {
                    int r = t >> 4;
                    inv[r] = sa;
                    inv[32 + r] = sb;
                }
            }
            __syncthreads();
            if (t < 64) inv[t] = 1.0f / sqrtf(inv[t]);
            __syncthreads();
            if (w < 4) {
                float* T = (ph == 0) ? Ml : Gl;
                #pragma unroll
                for (int rg = 0; rg < 4; ++rg) {
                    int row = wi * 16 + quad * 4 + rg;
                    int col = wj * 16 + l16;
                    T[row * 36 + col] = acc[rg] * inv[row] * inv[32 + col];
                }
            }
            __syncthreads();   // T visible; inv/tiles safe to reuse next phase
        }
        // DP
        if (t < 32) {
            float prev = 0.f, prevprev = 0.f;
            float m_next = Ml[t * 36 + 0], g_next = Gl[t * 36 + 0];
            for (int d = 2; d <= 64; ++d) {
                float m = m_next, g = g_next;
                int jn = d - t - 1;
                if (jn >= 0 && jn < 32) { m_next = Ml[t * 36 + jn]; g_next = Gl[t * 36 + jn]; }
                float up = __shfl_up(prev, 1);
                float dg = __shfl_up(prevprev, 1);
                if (t == 0) { up = 0.f; dg = 0.f; }
                int j = d - t - 1;
                float left = prev;
                float x0 = dg * 10.0f;
                float x1 = (g + up) * 10.0f;
                float x2 = (g + left) * 10.0f;
                float mx = fmaxf(x0, fmaxf(x1, x2));
                float lse = mx + __logf(__expf(x0 - mx) + __expf(x1 - mx) + __expf(x2 - mx));
                float val = m + 0.1f * lse;
                float cur = (j >= 1 && j <= 32) ? val : 0.f;
                prevprev = prev;
                prev = cur;
            }
            if (t == 31) ws[WS_FSD + b] = prev;
        }
    }
}

// wave-first block reduce over 4 waves (256 threads); 2 barriers
__device__ __forceinline__ float4 wbr4(float4 v, float4* redw, int t) {
    #pragma unroll
    for (int m = 1; m < 64; m <<= 1) {
        v.x += __shfl_xor(v.x, m);
        v.y += __shfl_xor(v.y, m);
        v.z += __shfl_xor(v.z, m);
        v.w += __shfl_xor(v.w, m);
    }
    if ((t & 63) == 0) redw[t >> 6] = v;
    __syncthreads();
    float4 r;
    r.x = redw[0].x + redw[1].x + redw[2].x + redw[3].x;
    r.y = redw[0].y + redw[1].y + redw[2].y + redw[3].y;
    r.z = redw[0].z + redw[1].z + redw[2].z + redw[3].z;
    r.w = redw[0].w + redw[1].w + redw[2].w + redw[3].w;
    __syncthreads();
    return r;
}

// ============ final combine: one block, 256 threads ============
__global__ __launch_bounds__(256) void final_kernel(
    const float* __restrict__ ai0, const float* __restrict__ ac0,
    const float* __restrict__ ab0, const float* __restrict__ vid0,
    const float* __restrict__ ai1, const float* __restrict__ ac1,
    const float* __restrict__ ab1, const float* __restrict__ vid1,
    const float* __restrict__ ws, float* __restrict__ out) {
    __shared__ float rs0[Bn], rs1[Bn], plsh[Bn];
    __shared__ __align__(16) float4 redw[4];
    int t = threadIdx.x;
    if (t < Bn) {
        float s0 = 0.f, s1 = 0.f, pp = 0.f;
        for (int c = 0; c < NCLS; ++c) {
            float a = vid0[t * NCLS + c], bl = vid1[t * NCLS + c];
            s0 += a; s1 += bl; pp += a * bl;
        }
        rs0[t] = s0;
        rs1[t] = s1;
        plsh[t] = (pp > 0.f) ? 1.f : 0.f;
    }
    __syncthreads();

    float inst0 = 0.f, cont0 = 0.f, back0 = 0.f;
    float inst1 = 0.f, cont1 = 0.f, back1 = 0.f;
    for (int idx = t; idx < Bn * (NCLS + 1); idx += 256) {
        int b = idx / (NCLS + 1), c = idx % (NCLS + 1);
        float v0 = (c < NCLS) ? vid0[b * NCLS + c] : 0.f;
        float v1 = (c < NCLS) ? vid1[b * NCLS + c] : 0.f;
        float wI0 = (c < NCLS) ? (v0 / rs0[b]) : 0.f;
        float wC0 = ((c < NCLS) ? v0 : 1.f) / (rs0[b] + 1.f);
        float wI1 = (c < NCLS) ? (v1 / rs1[b]) : 0.f;
        float wC1 = ((c < NCLS) ? v1 : 1.f) / (rs1[b] + 1.f);
        inst0 += logf(ai0[idx] + 1e-10f) * wI0;
        cont0 += logf(ac0[idx] + 1e-10f) * wC0;
        inst1 += logf(ai1[idx] + 1e-10f) * wI1;
        cont1 += logf(ac1[idx] + 1e-10f) * wC1;
        if (c == NCLS) {
            back0 += logf(ab0[idx] + 1e-10f);
            back1 += logf(ab1[idx] + 1e-10f);
        }
    }

    float g0 = 0.f, s0v = 0.f, g1 = 0.f, s1v = 0.f;
    if (t < 128) {
        float4 g = *(const float4*)&ws[WS_GS + t * 4];
        g0 = g.x; s0v = g.y; g1 = g.z; s1v = g.w;
    }

    float fv0 = 0.f, fv1 = 0.f;
    if (t < Bn) {
        const float* nm = ws + WS_NORM;
        {
            float ni = nm[0 * Bn + t], nc = nm[1 * Bn + t], nb = nm[2 * Bn + t];
            float f1 = fmaxf(50.0f - ni + nc, 0.f);
            float f2 = fmaxf(50.0f - nc + nb, 0.f);
            float f = f1 + f2 + nb;
            fv0 = f * f;
        }
        {
            float ni = nm[3 * Bn + t], nc = nm[4 * Bn + t], nb = nm[5 * Bn + t];
            float f1 = fmaxf(50.0f - ni + nc, 0.f);
            float f2 = fmaxf(50.0f - nc + nb, 0.f);
            float f = f1 + f2 + nb;
            fv1 = f * f;
        }
    }

    float posL = 0.f, negL = 0.f, posF = 0.f, negF = 0.f, pln = 0.f;
    if (t < Bn) {
        float pl = plsh[t];
        float lv = ws[WS_LCS + t];
        float fv = ws[WS_FSD + t];
        posL = lv * pl; negL = lv * (1.f - pl);
        posF = fv * pl; negF = fv * (1.f - pl);
        pln = pl;
    }

    float4 r1 = wbr4({inst0, cont0, back0, inst1}, redw, t);
    float4 r2 = wbr4({cont1, back1, g0, s0v}, redw, t);
    float4 r3 = wbr4({g1, s1v, fv0, fv1}, redw, t);
    float4 r4 = wbr4({posL, negL, posF, negF}, redw, t);
    float4 r5 = wbr4({pln, 0.f, 0.f, 0.f}, redw, t);

    if (t == 0) {
        float cls0 = -(r1.x + r1.y + r1.z) / (float)Bn;
        float cls1 = -(r1.w + r2.x + r2.y) / (float)Bn;
        float guide0 = r2.z / (float)Bn;
        float sparse0 = r2.w / (float)(Bn * 2);
        float guide1 = r3.x / (float)Bn;
        float sparse1 = r3.y / (float)(Bn * 2);
        float sFeat0 = r3.z / (float)Bn;
        float sFeat1 = r3.w / (float)Bn;
        float loss0 = cls0 + 1.0f * guide0 + 5e-05f * sFeat0 + 8e-05f * sparse0;
        float loss1 = cls1 + 1.0f * guide1 + 5e-05f * sFeat1 + 8e-05f * sparse1;
        float acm = 0.5f * (loss0 + loss1);
        float posn = r5.x;
        float negn = (float)Bn - posn;
        float lcs_loss = r4.y / (negn + 1e-10f) - r4.x / (posn + 1e-10f);
        float fsd_loss = r4.w / (negn + 1e-10f) - r4.z / (posn + 1e-10f);
        out[0] = acm + 0.01f * lcs_loss + 0.01f * fsd_loss;
    }
}

extern "C" void kernel_launch(void* const* d_in, const int* in_sizes, int n_in,
                              void* d_out, int out_size, void* d_ws, size_t ws_size,
                              hipStream_t stream) {
    (void)in_sizes; (void)n_in; (void)out_size; (void)ws_size;
    const float* ai0  = (const float*)d_in[0];
    const float* ac0  = (const float*)d_in[1];
    const float* ab0  = (const float*)d_in[2];
    const float* vid0 = (const float*)d_in[3];
    const float* att0 = (const float*)d_in[4];
    const float* fi0  = (const float*)d_in[5];
    const float* fc0  = (const float*)d_in[6];
    const float* fb0  = (const float*)d_in[7];
    const float* cas0 = (const float*)d_in[8];
    const float* lcs0 = (const float*)d_in[9];
    const float* fsdA0 = (const float*)d_in[10];
    const float* ai1  = (const float*)d_in[12];
    const float* ac1  = (const float*)d_in[13];
    const float* ab1  = (const float*)d_in[14];
    const float* vid1 = (const float*)d_in[15];
    const float* att1 = (const float*)d_in[16];
    const float* fi1  = (const float*)d_in[17];
    const float* fc1  = (const float*)d_in[18];
    const float* fb1  = (const float*)d_in[19];
    const float* cas1 = (const float*)d_in[20];
    const float* lcs1 = (const float*)d_in[21];
    const float* fsdA1 = (const float*)d_in[22];
    const float* fsdB1 = (const float*)d_in[23];

    float* ws = (float*)d_ws;

    mega_kernel<<<NBLK, 512, 0, stream>>>(
        lcs0, lcs1, fsdA0, fsdA1, fsdB1, vid0, vid1, cas0, att0, cas1, att1,
        fi0, fc0, fb0, fi1, fc1, fb1, ws);
    final_kernel<<<1, 256, 0, stream>>>(ai0, ac0, ab0, vid0, ai1, ac1, ab1, vid1,
                                        ws, (float*)d_out);
}